// Round 5
// baseline (141.892 us; speedup 1.0000x reference)
//
#include <hip/hip_runtime.h>
#include <stdint.h>

// ---------------------------------------------------------------------------
// VCSMC step on MI355X. Bit-exact JAX threefry RNG (partitionable semantics).
// R5: 3-kernel pipeline. k_sf = setup + site-logits fused; k_lorig scans pw[]
// for relevance (no used[] init hazard) AND computes the per-k merged-node
// site term inline (L1-hot re-reads of slots i1,i2); k_out is a trivial
// single-block combine.
//   expm collapse: Q^2 = -Q  =>  expm(b*Q) = I + (1-e^-b) Q (exact).
// ---------------------------------------------------------------------------

#define TF_ROT(x0,x1,r) { x0 += x1; x1 = ((x1<<(r))|(x1>>(32-(r)))); x1 ^= x0; }

__host__ __device__ inline void tf2x32(uint32_t k0, uint32_t k1,
                                       uint32_t x0, uint32_t x1,
                                       uint32_t& o0, uint32_t& o1) {
  uint32_t ks2 = k0 ^ k1 ^ 0x1BD11BDAu;
  x0 += k0; x1 += k1;
  TF_ROT(x0,x1,13) TF_ROT(x0,x1,15) TF_ROT(x0,x1,26) TF_ROT(x0,x1,6)
  x0 += k1; x1 += ks2 + 1u;
  TF_ROT(x0,x1,17) TF_ROT(x0,x1,29) TF_ROT(x0,x1,16) TF_ROT(x0,x1,24)
  x0 += ks2; x1 += k0 + 2u;
  TF_ROT(x0,x1,13) TF_ROT(x0,x1,15) TF_ROT(x0,x1,26) TF_ROT(x0,x1,6)
  x0 += k0; x1 += k1 + 3u;
  TF_ROT(x0,x1,17) TF_ROT(x0,x1,29) TF_ROT(x0,x1,16) TF_ROT(x0,x1,24)
  x0 += k1; x1 += ks2 + 4u;
  TF_ROT(x0,x1,13) TF_ROT(x0,x1,15) TF_ROT(x0,x1,26) TF_ROT(x0,x1,6)
  x0 += ks2; x1 += k0 + 5u;
  o0 = x0; o1 = x1;
}

struct Keys {
  uint32_t kres0, kres1;
  uint32_t k2i0, k2i1;
  uint32_t k1o0, k1o1;
  uint32_t k2o0, k2o1;
  uint32_t ku10, ku11;
  uint32_t ku20, ku21;
};

__device__ inline uint32_t rb_fold(uint32_t k0, uint32_t k1, uint32_t i) {
  uint32_t o0, o1;
  tf2x32(k0, k1, 0u, i, o0, o1);
  return o0 ^ o1;
}

__device__ inline float u01f(uint32_t b) {
  return __uint_as_float((b >> 9) | 0x3F800000u) - 1.0f;
}

#define TINYF 1.17549435e-38f

// ---------------------------------------------------------------------------
// Kernel 1: blocks 0..255 = per-particle setup; blocks 256..259 = esl.
// ---------------------------------------------------------------------------
__global__ __launch_bounds__(256) void k_sf(
    const float* __restrict__ logw, const float* __restrict__ b1r,
    const float* __restrict__ b2r, const int* __restrict__ lc,
    const float* __restrict__ emb, const float* __restrict__ logpi,
    const float* __restrict__ Wstat, const float* __restrict__ ldf,
    const float* __restrict__ site, const float* __restrict__ Wsite,
    float* __restrict__ eslw, float* __restrict__ enlm,
    float* __restrict__ w1w, float* __restrict__ w2w,
    float* __restrict__ cw, int* __restrict__ pw, int* __restrict__ i1w,
    int* __restrict__ i2w, Keys kk) {
  int b = blockIdx.x, tid = threadIdx.x;
  if (b >= 256) {
    // ---- site exp-logits ----
    int s = (b - 256) * 256 + tid;
    float a0 = 0.f, a1 = 0.f, a2 = 0.f, a3 = 0.f;
#pragma unroll
    for (int c = 0; c < 16; c++) {
      float sc = site[s * 16 + c];
      a0 += sc * Wsite[c * 4 + 0];
      a1 += sc * Wsite[c * 4 + 1];
      a2 += sc * Wsite[c * 4 + 2];
      a3 += sc * Wsite[c * 4 + 3];
    }
    float4 v; v.x = __expf(a0); v.y = __expf(a1); v.z = __expf(a2); v.w = __expf(a3);
    ((float4*)eslw)[s] = v;
    return;
  }
  int k = b;
  __shared__ float sval[256];
  __shared__ int   sidx[256];
  __shared__ int   sh_i1, sh_i2;

  {
    uint32_t bb = rb_fold(kk.kres0, kk.kres1, (uint32_t)(k * 256 + tid));
    float u = fmaxf(TINYF, u01f(bb) + TINYF);
    float g = -logf(-logf(u));            // precise: discrete decision
    sval[tid] = g + logw[tid];
    sidx[tid] = tid;
  }
  __syncthreads();
  for (int st = 128; st > 0; st >>= 1) {
    if (tid < st) {
      float va = sval[tid], vb = sval[tid + st];
      int ia = sidx[tid], ib = sidx[tid + st];
      if (vb > va || (vb == va && ib < ia)) { sval[tid] = vb; sidx[tid] = ib; }
    }
    __syncthreads();
  }
  int p = sidx[0];

  if (tid == 0) {
    uint32_t i = rb_fold(kk.k2i0, kk.k2i1, (uint32_t)k) & 15u;
    uint32_t h = rb_fold(kk.k1o0, kk.k1o1, (uint32_t)k) % 15u;
    uint32_t l = rb_fold(kk.k2o0, kk.k2o1, (uint32_t)k) % 15u;
    uint32_t off = 1u + (h + l) % 15u;
    uint32_t j = (i + off) & 15u;
    int i1 = (int)(i < j ? i : j);
    int i2 = (int)(i < j ? j : i);
    sh_i1 = i1; sh_i2 = i2;

    const float SUBR = 1.0f - 1e-6f;
    float u1 = fmaxf(1e-6f, u01f(rb_fold(kk.ku10, kk.ku11, (uint32_t)k)) * SUBR + 1e-6f);
    float u2 = fmaxf(1e-6f, u01f(rb_fold(kk.ku20, kk.ku21, (uint32_t)k)) * SUBR + 1e-6f);
    float b1 = -0.1f * logf(u1);
    float b2 = -0.1f * logf(u2);
    w1w[k] = 1.0f - expf(-b1);
    w2w[k] = 1.0f - expf(-b2);
    i1w[k] = i1; i2w[k] = i2; pw[k] = p;

    float sb = b1 + b2;
    for (int r = 0; r < 16; r++) sb += b1r[p * 16 + r] + b2r[p * 16 + r];
    float prior = -sb / 0.1f - 34.0f * logf(0.1f);

    float topo_sum = 0.0f; int cnt = 0;
    for (int t = 0; t < 15; t++) {
      int lct;
      if (t == i1)      lct = lc[p * 16 + i1] + lc[p * 16 + i2];
      else if (t == i2) lct = lc[p * 16 + 15];
      else              lct = lc[p * 16 + t];
      int ti = 2 * lct - 3; ti = ti < 0 ? 0 : (ti > 63 ? 63 : ti);
      if (lct >= 2) topo_sum -= ldf[ti];
      if (lct > 1) cnt++;
    }
    float log_v_minus = logf(fmaxf((float)cnt, 1.0f));
    float log_v_plus = logf(120.0f);
    cw[k] = prior + topo_sum - logpi[p] + log_v_minus - log_v_plus;
  }
  __syncthreads();

  if (tid < 4) {
    int a = tid, i1 = sh_i1, i2 = sh_i2, p2 = sidx[0];
    const float* e1 = emb + ((size_t)p2 * 16 + i1) * 64;
    const float* e2 = emb + ((size_t)p2 * 16 + i2) * 64;
    float acc = 0.0f;
    for (int d = 0; d < 64; d++) acc += 0.5f * (e1[d] + e2[d]) * Wstat[d * 4 + a];
    enlm[k * 4 + a] = __expf(acc);
  }
}

// ---------------------------------------------------------------------------
// Kernel 2: grid (4 sblk, 256 p) x 256. Scans pw[] for the k-list of this p
// (early exit if empty); computes Lorig partials for all 16 slots AND the
// per-k merged-node term (slots i1,i2 re-read L1-hot).
// ---------------------------------------------------------------------------
__global__ __launch_bounds__(256) void k_lorig(
    const float* __restrict__ lfg, const float* __restrict__ eslw,
    const float* __restrict__ emb, const float* __restrict__ Wstat,
    const int* __restrict__ pw, const int* __restrict__ i1w,
    const int* __restrict__ i2w, const float* __restrict__ w1w,
    const float* __restrict__ w2w, const float* __restrict__ enlm,
    float* __restrict__ Lpart, float* __restrict__ Lm) {
  int p = blockIdx.y, sblk = blockIdx.x, tid = threadIdx.x;
  __shared__ int klist[256];
  __shared__ int kcount;
  __shared__ float enl[64];
  __shared__ float sred[16 * 4];
  __shared__ float sredm[4];
  if (tid == 0) kcount = 0;
  __syncthreads();
  if (pw[tid] == p) { int sl = atomicAdd(&kcount, 1); klist[sl] = tid; }
  __syncthreads();
  if (kcount == 0) return;

  if (tid < 64) {
    int t = tid >> 2, a = tid & 3;
    const float4* e4 = (const float4*)(emb + ((size_t)p * 16 + t) * 64);
    float acc = 0.0f;
#pragma unroll
    for (int d4 = 0; d4 < 16; d4++) {
      float4 e = e4[d4];
      acc += e.x * Wstat[(d4 * 4 + 0) * 4 + a] + e.y * Wstat[(d4 * 4 + 1) * 4 + a] +
             e.z * Wstat[(d4 * 4 + 2) * 4 + a] + e.w * Wstat[(d4 * 4 + 3) * 4 + a];
    }
    enl[tid] = __expf(acc);
  }
  __syncthreads();
  int s = sblk * 256 + tid;
  const float4 esl = ((const float4*)eslw)[s];
  const float* base = lfg + (size_t)p * 65536;

  // ---- Lorig over all 16 slots (log2 domain) ----
  float acc[16];
#pragma unroll
  for (int t = 0; t < 16; t++) {
    float4 lf = *(const float4*)(base + t * 4096 + s * 4);
    float w0 = enl[t * 4 + 0] * esl.x, w1 = enl[t * 4 + 1] * esl.y;
    float w2 = enl[t * 4 + 2] * esl.z, w3 = enl[t * 4 + 3] * esl.w;
    float S1 = w0 + w1 + w2 + w3;
    float S2 = __expf(lf.x) * w0 + __expf(lf.y) * w1 +
               __expf(lf.z) * w2 + __expf(lf.w) * w3;
    acc[t] = __log2f(S2) - __log2f(S1);
  }
#pragma unroll
  for (int t = 0; t < 16; t++) {
    float v = acc[t];
    for (int o = 32; o > 0; o >>= 1) v += __shfl_down(v, o, 64);
    if ((tid & 63) == 0) sred[t * 4 + (tid >> 6)] = v;
  }
  __syncthreads();
  if (tid < 16) {
    float s4 = sred[tid * 4 + 0] + sred[tid * 4 + 1] + sred[tid * 4 + 2] + sred[tid * 4 + 3];
    Lpart[((size_t)p * 4 + sblk) * 16 + tid] = s4 * 0.69314718056f;  // ln2
  }

  // ---- merged-node term for each k that resampled p ----
  for (int q = 0; q < kcount; q++) {
    int kq = klist[q];
    int i1 = i1w[kq], i2 = i2w[kq];
    float w1 = w1w[kq], w2 = w2w[kq];
    float om1 = 1.0f - w1, om2 = 1.0f - w2;
    float m0 = enlm[kq * 4 + 0], m1 = enlm[kq * 4 + 1];
    float m2 = enlm[kq * 4 + 2], m3 = enlm[kq * 4 + 3];
    float t0 = m0 * esl.x, t1 = m1 * esl.y, t2 = m2 * esl.z, t3 = m3 * esl.w;
    float T = t0 + t1 + t2 + t3;
    float invT = 1.0f / T;
    float4 lf1 = *(const float4*)(base + i1 * 4096 + s * 4);   // L1-hot
    float4 lf2 = *(const float4*)(base + i2 * 4096 + s * 4);
    float f10 = __expf(lf1.x), f11 = __expf(lf1.y), f12 = __expf(lf1.z), f13 = __expf(lf1.w);
    float f20 = __expf(lf2.x), f21 = __expf(lf2.y), f22 = __expf(lf2.z), f23 = __expf(lf2.w);
    float dot1 = (t0 * f10 + t1 * f11 + t2 * f12 + t3 * f13) * invT;
    float dot2 = (t0 * f20 + t1 * f21 + t2 * f22 + t3 * f23) * invT;
    float n0 = __logf(om1 * f10 + w1 * dot1 + 1e-30f) + __logf(om2 * f20 + w2 * dot2 + 1e-30f);
    float n1 = __logf(om1 * f11 + w1 * dot1 + 1e-30f) + __logf(om2 * f21 + w2 * dot2 + 1e-30f);
    float n2 = __logf(om1 * f12 + w1 * dot1 + 1e-30f) + __logf(om2 * f22 + w2 * dot2 + 1e-30f);
    float n3 = __logf(om1 * f13 + w1 * dot1 + 1e-30f) + __logf(om2 * f23 + w2 * dot2 + 1e-30f);
    float S2 = __expf(n0) * t0 + __expf(n1) * t1 + __expf(n2) * t2 + __expf(n3) * t3;
    float tot = __logf(S2) - __logf(T);
    for (int o = 32; o > 0; o >>= 1) tot += __shfl_down(tot, o, 64);
    if ((tid & 63) == 0) sredm[tid >> 6] = tot;
    __syncthreads();
    if (tid == 0)
      Lm[kq * 4 + sblk] = sredm[0] + sredm[1] + sredm[2] + sredm[3];
    __syncthreads();
  }
}

// ---------------------------------------------------------------------------
// Kernel 3: final combine, one block of 256 (thread = k).
// ---------------------------------------------------------------------------
__global__ __launch_bounds__(256) void k_out(
    const float* __restrict__ cw, const float* __restrict__ Lpart,
    const float* __restrict__ Lm, const int* __restrict__ pw,
    const int* __restrict__ i1w, const int* __restrict__ i2w,
    float* __restrict__ out) {
  int k = threadIdx.x;
  int p = pw[k], i1 = i1w[k], i2 = i2w[k];
  const float* Lp = Lpart + (size_t)p * 64;
  float sum = cw[k];
#pragma unroll
  for (int sb = 0; sb < 4; sb++) {
    float ss = Lm[k * 4 + sb];
    for (int t = 0; t < 16; t++)
      if (t != i1 && t != i2) ss += Lp[sb * 16 + t];
    sum += ss;
  }
  out[k] = sum;
}

// ---------------------------------------------------------------------------
extern "C" void kernel_launch(void* const* d_in, const int* in_sizes, int n_in,
                              void* d_out, int out_size, void* d_ws, size_t ws_size,
                              hipStream_t stream) {
  const float* logw  = (const float*)d_in[0];
  const float* b1r   = (const float*)d_in[1];
  const float* b2r   = (const float*)d_in[2];
  const int*   lc    = (const int*)d_in[3];
  const float* emb   = (const float*)d_in[4];
  const float* lfg   = (const float*)d_in[5];
  const float* logpi = (const float*)d_in[6];
  const float* site  = (const float*)d_in[7];
  const float* Wstat = (const float*)d_in[8];
  const float* Wsite = (const float*)d_in[9];
  const float* ldf   = (const float*)d_in[10];

  char* w = (char*)d_ws;
  float* eslw  = (float*)w; w += 1024 * 4 * 4;
  float* enlm  = (float*)w; w += 256 * 4 * 4;
  float* w1w   = (float*)w; w += 256 * 4;
  float* w2w   = (float*)w; w += 256 * 4;
  float* cw    = (float*)w; w += 256 * 4;
  int*   pw    = (int*)w;   w += 256 * 4;
  int*   i1w   = (int*)w;   w += 256 * 4;
  int*   i2w   = (int*)w;   w += 256 * 4;
  float* Lpart = (float*)w; w += 256 * 64 * 4;
  float* Lm    = (float*)w; w += 256 * 4 * 4;

  uint32_t S0[5], S1[5];
  for (uint32_t i = 0; i < 5; i++) tf2x32(0u, 42u, 0u, i, S0[i], S1[i]);
  Keys kk;
  kk.kres0 = S0[0]; kk.kres1 = S1[0];
  kk.ku10  = S0[3]; kk.ku11  = S1[3];
  kk.ku20  = S0[4]; kk.ku21  = S1[4];
  {
    uint32_t a0, a1, b0, b1;
    tf2x32(S0[1], S1[1], 0u, 0u, a0, a1);
    tf2x32(S0[1], S1[1], 0u, 1u, b0, b1);
    (void)a0; (void)a1;
    kk.k2i0 = b0; kk.k2i1 = b1;
  }
  {
    uint32_t a0, a1, b0, b1;
    tf2x32(S0[2], S1[2], 0u, 0u, a0, a1);
    tf2x32(S0[2], S1[2], 0u, 1u, b0, b1);
    kk.k1o0 = a0; kk.k1o1 = a1;
    kk.k2o0 = b0; kk.k2o1 = b1;
  }

  k_sf<<<260, 256, 0, stream>>>(logw, b1r, b2r, lc, emb, logpi, Wstat, ldf,
                                site, Wsite, eslw, enlm, w1w, w2w, cw,
                                pw, i1w, i2w, kk);
  dim3 gC(4, 256);
  k_lorig<<<gC, 256, 0, stream>>>(lfg, eslw, emb, Wstat, pw, i1w, i2w,
                                  w1w, w2w, enlm, Lpart, Lm);
  k_out<<<1, 256, 0, stream>>>(cw, Lpart, Lm, pw, i1w, i2w, (float*)d_out);
}

// Round 6
// 134.097 us; speedup vs baseline: 1.0581x; 1.0581x over previous
//
#include <hip/hip_runtime.h>
#include <stdint.h>

// ---------------------------------------------------------------------------
// VCSMC step on MI355X. Bit-exact JAX threefry RNG (partitionable semantics).
// R6: revert R5's serial fusion (regressed: skewed kcount serialized the
// dominant kernel). 3 launches, all block-parallel:
//   k_sf  (260 blocks): per-particle setup + site exp-logits.
//   k_mid (5 x 256):    x<4 -> Lorig partials for particle p (pw[]-scan
//                       early-exit); x==4 -> merged-node site term for k.
//   k_out (1 x 256):    final combine.
//   expm collapse: Q^2 = -Q  =>  expm(b*Q) = I + (1-e^-b) Q (exact).
// ---------------------------------------------------------------------------

#define TF_ROT(x0,x1,r) { x0 += x1; x1 = ((x1<<(r))|(x1>>(32-(r)))); x1 ^= x0; }

__host__ __device__ inline void tf2x32(uint32_t k0, uint32_t k1,
                                       uint32_t x0, uint32_t x1,
                                       uint32_t& o0, uint32_t& o1) {
  uint32_t ks2 = k0 ^ k1 ^ 0x1BD11BDAu;
  x0 += k0; x1 += k1;
  TF_ROT(x0,x1,13) TF_ROT(x0,x1,15) TF_ROT(x0,x1,26) TF_ROT(x0,x1,6)
  x0 += k1; x1 += ks2 + 1u;
  TF_ROT(x0,x1,17) TF_ROT(x0,x1,29) TF_ROT(x0,x1,16) TF_ROT(x0,x1,24)
  x0 += ks2; x1 += k0 + 2u;
  TF_ROT(x0,x1,13) TF_ROT(x0,x1,15) TF_ROT(x0,x1,26) TF_ROT(x0,x1,6)
  x0 += k0; x1 += k1 + 3u;
  TF_ROT(x0,x1,17) TF_ROT(x0,x1,29) TF_ROT(x0,x1,16) TF_ROT(x0,x1,24)
  x0 += k1; x1 += ks2 + 4u;
  TF_ROT(x0,x1,13) TF_ROT(x0,x1,15) TF_ROT(x0,x1,26) TF_ROT(x0,x1,6)
  x0 += ks2; x1 += k0 + 5u;
  o0 = x0; o1 = x1;
}

struct Keys {
  uint32_t kres0, kres1;
  uint32_t k2i0, k2i1;
  uint32_t k1o0, k1o1;
  uint32_t k2o0, k2o1;
  uint32_t ku10, ku11;
  uint32_t ku20, ku21;
};

__device__ inline uint32_t rb_fold(uint32_t k0, uint32_t k1, uint32_t i) {
  uint32_t o0, o1;
  tf2x32(k0, k1, 0u, i, o0, o1);
  return o0 ^ o1;
}

__device__ inline float u01f(uint32_t b) {
  return __uint_as_float((b >> 9) | 0x3F800000u) - 1.0f;
}

#define TINYF 1.17549435e-38f

// ---------------------------------------------------------------------------
// Kernel 1: blocks 0..255 = per-particle setup; blocks 256..259 = esl.
// ---------------------------------------------------------------------------
__global__ __launch_bounds__(256) void k_sf(
    const float* __restrict__ logw, const float* __restrict__ b1r,
    const float* __restrict__ b2r, const int* __restrict__ lc,
    const float* __restrict__ emb, const float* __restrict__ logpi,
    const float* __restrict__ Wstat, const float* __restrict__ ldf,
    const float* __restrict__ site, const float* __restrict__ Wsite,
    float* __restrict__ eslw, float* __restrict__ enlm,
    float* __restrict__ w1w, float* __restrict__ w2w,
    float* __restrict__ cw, int* __restrict__ pw, int* __restrict__ i1w,
    int* __restrict__ i2w, Keys kk) {
  int b = blockIdx.x, tid = threadIdx.x;
  if (b >= 256) {
    int s = (b - 256) * 256 + tid;
    float a0 = 0.f, a1 = 0.f, a2 = 0.f, a3 = 0.f;
#pragma unroll
    for (int c = 0; c < 16; c++) {
      float sc = site[s * 16 + c];
      a0 += sc * Wsite[c * 4 + 0];
      a1 += sc * Wsite[c * 4 + 1];
      a2 += sc * Wsite[c * 4 + 2];
      a3 += sc * Wsite[c * 4 + 3];
    }
    float4 v; v.x = __expf(a0); v.y = __expf(a1); v.z = __expf(a2); v.w = __expf(a3);
    ((float4*)eslw)[s] = v;
    return;
  }
  int k = b;
  __shared__ float sval[256];
  __shared__ int   sidx[256];
  __shared__ int   sh_i1, sh_i2;

  {
    uint32_t bb = rb_fold(kk.kres0, kk.kres1, (uint32_t)(k * 256 + tid));
    float u = fmaxf(TINYF, u01f(bb) + TINYF);
    float g = -logf(-logf(u));            // precise: discrete decision
    sval[tid] = g + logw[tid];
    sidx[tid] = tid;
  }
  __syncthreads();
  for (int st = 128; st > 0; st >>= 1) {
    if (tid < st) {
      float va = sval[tid], vb = sval[tid + st];
      int ia = sidx[tid], ib = sidx[tid + st];
      if (vb > va || (vb == va && ib < ia)) { sval[tid] = vb; sidx[tid] = ib; }
    }
    __syncthreads();
  }
  int p = sidx[0];

  if (tid == 0) {
    uint32_t i = rb_fold(kk.k2i0, kk.k2i1, (uint32_t)k) & 15u;
    uint32_t h = rb_fold(kk.k1o0, kk.k1o1, (uint32_t)k) % 15u;
    uint32_t l = rb_fold(kk.k2o0, kk.k2o1, (uint32_t)k) % 15u;
    uint32_t off = 1u + (h + l) % 15u;
    uint32_t j = (i + off) & 15u;
    int i1 = (int)(i < j ? i : j);
    int i2 = (int)(i < j ? j : i);
    sh_i1 = i1; sh_i2 = i2;

    const float SUBR = 1.0f - 1e-6f;
    float u1 = fmaxf(1e-6f, u01f(rb_fold(kk.ku10, kk.ku11, (uint32_t)k)) * SUBR + 1e-6f);
    float u2 = fmaxf(1e-6f, u01f(rb_fold(kk.ku20, kk.ku21, (uint32_t)k)) * SUBR + 1e-6f);
    float b1 = -0.1f * logf(u1);
    float b2 = -0.1f * logf(u2);
    w1w[k] = 1.0f - expf(-b1);
    w2w[k] = 1.0f - expf(-b2);
    i1w[k] = i1; i2w[k] = i2; pw[k] = p;

    float sb = b1 + b2;
    for (int r = 0; r < 16; r++) sb += b1r[p * 16 + r] + b2r[p * 16 + r];
    float prior = -sb / 0.1f - 34.0f * logf(0.1f);

    float topo_sum = 0.0f; int cnt = 0;
    for (int t = 0; t < 15; t++) {
      int lct;
      if (t == i1)      lct = lc[p * 16 + i1] + lc[p * 16 + i2];
      else if (t == i2) lct = lc[p * 16 + 15];
      else              lct = lc[p * 16 + t];
      int ti = 2 * lct - 3; ti = ti < 0 ? 0 : (ti > 63 ? 63 : ti);
      if (lct >= 2) topo_sum -= ldf[ti];
      if (lct > 1) cnt++;
    }
    float log_v_minus = logf(fmaxf((float)cnt, 1.0f));
    float log_v_plus = logf(120.0f);
    cw[k] = prior + topo_sum - logpi[p] + log_v_minus - log_v_plus;
  }
  __syncthreads();

  if (tid < 4) {
    int a = tid, i1 = sh_i1, i2 = sh_i2, p2 = sidx[0];
    const float* e1 = emb + ((size_t)p2 * 16 + i1) * 64;
    const float* e2 = emb + ((size_t)p2 * 16 + i2) * 64;
    float acc = 0.0f;
    for (int d = 0; d < 64; d++) acc += 0.5f * (e1[d] + e2[d]) * Wstat[d * 4 + a];
    enlm[k * 4 + a] = __expf(acc);
  }
}

// ---------------------------------------------------------------------------
// Kernel 2: grid (5, 256) x 256.
//   blockIdx.x < 4 : Lorig partials, sblk = x, particle p = y (skip if p
//                    never resampled — benign-race LDS flag from pw[] scan).
//   blockIdx.x == 4: merged-node site term for k = y -> Lm[k].
// ---------------------------------------------------------------------------
__global__ __launch_bounds__(256) void k_mid(
    const float* __restrict__ lfg, const float* __restrict__ eslw,
    const float* __restrict__ emb, const float* __restrict__ Wstat,
    const int* __restrict__ pw, const int* __restrict__ i1w,
    const int* __restrict__ i2w, const float* __restrict__ w1w,
    const float* __restrict__ w2w, const float* __restrict__ enlm,
    float* __restrict__ Lpart, float* __restrict__ Lm) {
  int tid = threadIdx.x;
  if (blockIdx.x == 4) {
    // ---- merged-node term for k, 4 sites per thread ----
    int k = blockIdx.y;
    __shared__ float sredm[4];
    int p = pw[k], i1 = i1w[k], i2 = i2w[k];
    float w1 = w1w[k], w2 = w2w[k];
    float om1 = 1.0f - w1, om2 = 1.0f - w2;
    float m0 = enlm[k * 4 + 0], m1 = enlm[k * 4 + 1];
    float m2 = enlm[k * 4 + 2], m3 = enlm[k * 4 + 3];
    const float* base = lfg + (size_t)p * 65536;
    float tot = 0.0f;
#pragma unroll
    for (int c = 0; c < 4; c++) {
      int s = c * 256 + tid;
      const float4 esl = ((const float4*)eslw)[s];
      float t0 = m0 * esl.x, t1 = m1 * esl.y, t2 = m2 * esl.z, t3 = m3 * esl.w;
      float T = t0 + t1 + t2 + t3;
      float invT = 1.0f / T;
      float4 lf1 = *(const float4*)(base + i1 * 4096 + s * 4);
      float4 lf2 = *(const float4*)(base + i2 * 4096 + s * 4);
      float f10 = __expf(lf1.x), f11 = __expf(lf1.y), f12 = __expf(lf1.z), f13 = __expf(lf1.w);
      float f20 = __expf(lf2.x), f21 = __expf(lf2.y), f22 = __expf(lf2.z), f23 = __expf(lf2.w);
      float dot1 = (t0 * f10 + t1 * f11 + t2 * f12 + t3 * f13) * invT;
      float dot2 = (t0 * f20 + t1 * f21 + t2 * f22 + t3 * f23) * invT;
      float n0 = __logf(om1 * f10 + w1 * dot1 + 1e-30f) + __logf(om2 * f20 + w2 * dot2 + 1e-30f);
      float n1 = __logf(om1 * f11 + w1 * dot1 + 1e-30f) + __logf(om2 * f21 + w2 * dot2 + 1e-30f);
      float n2 = __logf(om1 * f12 + w1 * dot1 + 1e-30f) + __logf(om2 * f22 + w2 * dot2 + 1e-30f);
      float n3 = __logf(om1 * f13 + w1 * dot1 + 1e-30f) + __logf(om2 * f23 + w2 * dot2 + 1e-30f);
      float S2 = __expf(n0) * t0 + __expf(n1) * t1 + __expf(n2) * t2 + __expf(n3) * t3;
      tot += __logf(S2) - __logf(T);
    }
    for (int o = 32; o > 0; o >>= 1) tot += __shfl_down(tot, o, 64);
    if ((tid & 63) == 0) sredm[tid >> 6] = tot;
    __syncthreads();
    if (tid == 0) Lm[k] = sredm[0] + sredm[1] + sredm[2] + sredm[3];
    return;
  }

  // ---- Lorig partials for particle p ----
  int p = blockIdx.y, sblk = blockIdx.x;
  __shared__ int kused;
  __shared__ float enl[64];
  __shared__ float sred[16 * 4];
  if (tid == 0) kused = 0;
  __syncthreads();
  if (pw[tid] == p) kused = 1;   // benign same-value race
  __syncthreads();
  if (kused == 0) return;

  if (tid < 64) {
    int t = tid >> 2, a = tid & 3;
    const float4* e4 = (const float4*)(emb + ((size_t)p * 16 + t) * 64);
    float acc = 0.0f;
#pragma unroll
    for (int d4 = 0; d4 < 16; d4++) {
      float4 e = e4[d4];
      acc += e.x * Wstat[(d4 * 4 + 0) * 4 + a] + e.y * Wstat[(d4 * 4 + 1) * 4 + a] +
             e.z * Wstat[(d4 * 4 + 2) * 4 + a] + e.w * Wstat[(d4 * 4 + 3) * 4 + a];
    }
    enl[tid] = __expf(acc);
  }
  __syncthreads();
  int s = sblk * 256 + tid;
  const float4 esl = ((const float4*)eslw)[s];
  const float* base = lfg + (size_t)p * 65536;

  float acc[16];
#pragma unroll
  for (int t = 0; t < 16; t++) {
    float4 lf = *(const float4*)(base + t * 4096 + s * 4);
    float w0 = enl[t * 4 + 0] * esl.x, w1 = enl[t * 4 + 1] * esl.y;
    float w2 = enl[t * 4 + 2] * esl.z, w3 = enl[t * 4 + 3] * esl.w;
    float S1 = w0 + w1 + w2 + w3;
    float S2 = __expf(lf.x) * w0 + __expf(lf.y) * w1 +
               __expf(lf.z) * w2 + __expf(lf.w) * w3;
    acc[t] = __log2f(S2) - __log2f(S1);
  }
#pragma unroll
  for (int t = 0; t < 16; t++) {
    float v = acc[t];
    for (int o = 32; o > 0; o >>= 1) v += __shfl_down(v, o, 64);
    if ((tid & 63) == 0) sred[t * 4 + (tid >> 6)] = v;
  }
  __syncthreads();
  if (tid < 16) {
    float s4 = sred[tid * 4 + 0] + sred[tid * 4 + 1] + sred[tid * 4 + 2] + sred[tid * 4 + 3];
    Lpart[((size_t)p * 4 + sblk) * 16 + tid] = s4 * 0.69314718056f;  // ln2
  }
}

// ---------------------------------------------------------------------------
// Kernel 3: final combine, one block of 256 (thread = k).
// ---------------------------------------------------------------------------
__global__ __launch_bounds__(256) void k_out(
    const float* __restrict__ cw, const float* __restrict__ Lpart,
    const float* __restrict__ Lm, const int* __restrict__ pw,
    const int* __restrict__ i1w, const int* __restrict__ i2w,
    float* __restrict__ out) {
  int k = threadIdx.x;
  int p = pw[k], i1 = i1w[k], i2 = i2w[k];
  const float* Lp = Lpart + (size_t)p * 64;
  float sum = cw[k] + Lm[k];
#pragma unroll
  for (int sb = 0; sb < 4; sb++) {
    float ss = 0.0f;
    for (int t = 0; t < 16; t++)
      if (t != i1 && t != i2) ss += Lp[sb * 16 + t];
    sum += ss;
  }
  out[k] = sum;
}

// ---------------------------------------------------------------------------
extern "C" void kernel_launch(void* const* d_in, const int* in_sizes, int n_in,
                              void* d_out, int out_size, void* d_ws, size_t ws_size,
                              hipStream_t stream) {
  const float* logw  = (const float*)d_in[0];
  const float* b1r   = (const float*)d_in[1];
  const float* b2r   = (const float*)d_in[2];
  const int*   lc    = (const int*)d_in[3];
  const float* emb   = (const float*)d_in[4];
  const float* lfg   = (const float*)d_in[5];
  const float* logpi = (const float*)d_in[6];
  const float* site  = (const float*)d_in[7];
  const float* Wstat = (const float*)d_in[8];
  const float* Wsite = (const float*)d_in[9];
  const float* ldf   = (const float*)d_in[10];

  char* w = (char*)d_ws;
  float* eslw  = (float*)w; w += 1024 * 4 * 4;
  float* enlm  = (float*)w; w += 256 * 4 * 4;
  float* w1w   = (float*)w; w += 256 * 4;
  float* w2w   = (float*)w; w += 256 * 4;
  float* cw    = (float*)w; w += 256 * 4;
  int*   pw    = (int*)w;   w += 256 * 4;
  int*   i1w   = (int*)w;   w += 256 * 4;
  int*   i2w   = (int*)w;   w += 256 * 4;
  float* Lpart = (float*)w; w += 256 * 64 * 4;
  float* Lm    = (float*)w; w += 256 * 4;

  uint32_t S0[5], S1[5];
  for (uint32_t i = 0; i < 5; i++) tf2x32(0u, 42u, 0u, i, S0[i], S1[i]);
  Keys kk;
  kk.kres0 = S0[0]; kk.kres1 = S1[0];
  kk.ku10  = S0[3]; kk.ku11  = S1[3];
  kk.ku20  = S0[4]; kk.ku21  = S1[4];
  {
    uint32_t a0, a1, b0, b1;
    tf2x32(S0[1], S1[1], 0u, 0u, a0, a1);
    tf2x32(S0[1], S1[1], 0u, 1u, b0, b1);
    (void)a0; (void)a1;
    kk.k2i0 = b0; kk.k2i1 = b1;
  }
  {
    uint32_t a0, a1, b0, b1;
    tf2x32(S0[2], S1[2], 0u, 0u, a0, a1);
    tf2x32(S0[2], S1[2], 0u, 1u, b0, b1);
    kk.k1o0 = a0; kk.k1o1 = a1;
    kk.k2o0 = b0; kk.k2o1 = b1;
  }

  k_sf<<<260, 256, 0, stream>>>(logw, b1r, b2r, lc, emb, logpi, Wstat, ldf,
                                site, Wsite, eslw, enlm, w1w, w2w, cw,
                                pw, i1w, i2w, kk);
  dim3 gM(5, 256);
  k_mid<<<gM, 256, 0, stream>>>(lfg, eslw, emb, Wstat, pw, i1w, i2w,
                                w1w, w2w, enlm, Lpart, Lm);
  k_out<<<1, 256, 0, stream>>>(cw, Lpart, Lm, pw, i1w, i2w, (float*)d_out);
}

// Round 7
// 129.555 us; speedup vs baseline: 1.0952x; 1.0351x over previous
//
#include <hip/hip_runtime.h>
#include <stdint.h>

// ---------------------------------------------------------------------------
// VCSMC step on MI355X. Bit-exact JAX threefry RNG (partitionable semantics).
// FINAL (= R4, best measured): 4 kernels, all block-parallel.
//   k_pre:   site exp-logits + used[] zero.
//   k_setup: per-particle RNG/resample/scalars + used[p]=1.
//   k_lorig: Lorig partials, early-exit on unused particles (~37% traffic cut).
//   k_fin:   merged-node site term (256x1024, fully parallel) + combine.
//   expm collapse: Q^2 = -Q  =>  expm(b*Q) = I + (1-e^-b) Q (exact).
// R5/R6 post-mortem: fusing the merged term into k_lorig (serial per-k loop)
// or replacing used[] with a pw[]-scan both regressed — keep this structure.
// ---------------------------------------------------------------------------

#define TF_ROT(x0,x1,r) { x0 += x1; x1 = ((x1<<(r))|(x1>>(32-(r)))); x1 ^= x0; }

__host__ __device__ inline void tf2x32(uint32_t k0, uint32_t k1,
                                       uint32_t x0, uint32_t x1,
                                       uint32_t& o0, uint32_t& o1) {
  uint32_t ks2 = k0 ^ k1 ^ 0x1BD11BDAu;
  x0 += k0; x1 += k1;
  TF_ROT(x0,x1,13) TF_ROT(x0,x1,15) TF_ROT(x0,x1,26) TF_ROT(x0,x1,6)
  x0 += k1; x1 += ks2 + 1u;
  TF_ROT(x0,x1,17) TF_ROT(x0,x1,29) TF_ROT(x0,x1,16) TF_ROT(x0,x1,24)
  x0 += ks2; x1 += k0 + 2u;
  TF_ROT(x0,x1,13) TF_ROT(x0,x1,15) TF_ROT(x0,x1,26) TF_ROT(x0,x1,6)
  x0 += k0; x1 += k1 + 3u;
  TF_ROT(x0,x1,17) TF_ROT(x0,x1,29) TF_ROT(x0,x1,16) TF_ROT(x0,x1,24)
  x0 += k1; x1 += ks2 + 4u;
  TF_ROT(x0,x1,13) TF_ROT(x0,x1,15) TF_ROT(x0,x1,26) TF_ROT(x0,x1,6)
  x0 += ks2; x1 += k0 + 5u;
  o0 = x0; o1 = x1;
}

struct Keys {
  uint32_t kres0, kres1;
  uint32_t k2i0, k2i1;
  uint32_t k1o0, k1o1;
  uint32_t k2o0, k2o1;
  uint32_t ku10, ku11;
  uint32_t ku20, ku21;
};

__device__ inline uint32_t rb_fold(uint32_t k0, uint32_t k1, uint32_t i) {
  uint32_t o0, o1;
  tf2x32(k0, k1, 0u, i, o0, o1);
  return o0 ^ o1;
}

__device__ inline float u01f(uint32_t b) {
  return __uint_as_float((b >> 9) | 0x3F800000u) - 1.0f;
}

#define TINYF 1.17549435e-38f

// ---------------------------------------------------------------------------
// Kernel A: esl[s][a] = exp(site logits); block 0 also zeroes used[].
// ---------------------------------------------------------------------------
__global__ __launch_bounds__(256) void k_pre(const float* __restrict__ site,
                                             const float* __restrict__ Wsite,
                                             float* __restrict__ eslw,
                                             int* __restrict__ used) {
  int tid = threadIdx.x;
  int s = blockIdx.x * 256 + tid;
  if (blockIdx.x == 0) used[tid] = 0;
  float a0 = 0.f, a1 = 0.f, a2 = 0.f, a3 = 0.f;
#pragma unroll
  for (int c = 0; c < 16; c++) {
    float sc = site[s * 16 + c];
    a0 += sc * Wsite[c * 4 + 0];
    a1 += sc * Wsite[c * 4 + 1];
    a2 += sc * Wsite[c * 4 + 2];
    a3 += sc * Wsite[c * 4 + 3];
  }
  float4 v; v.x = __expf(a0); v.y = __expf(a1); v.z = __expf(a2); v.w = __expf(a3);
  ((float4*)eslw)[s] = v;
}

// ---------------------------------------------------------------------------
// Kernel B: per-particle RNG + resampling + scalar constant + merged-node
// exp-logits + used-flag. Precise logf kept for discrete-RNG paths.
// ---------------------------------------------------------------------------
__global__ __launch_bounds__(256) void k_setup(
    const float* __restrict__ logw, const float* __restrict__ b1r,
    const float* __restrict__ b2r, const int* __restrict__ lc,
    const float* __restrict__ emb, const float* __restrict__ logpi,
    const float* __restrict__ Wstat, const float* __restrict__ ldf,
    float* __restrict__ enlm, float* __restrict__ w1w, float* __restrict__ w2w,
    float* __restrict__ cw, int* __restrict__ pw, int* __restrict__ i1w,
    int* __restrict__ i2w, int* __restrict__ used, Keys kk) {
  int k = blockIdx.x, tid = threadIdx.x;
  __shared__ float sval[256];
  __shared__ int   sidx[256];
  __shared__ int   sh_i1, sh_i2;

  {
    uint32_t b = rb_fold(kk.kres0, kk.kres1, (uint32_t)(k * 256 + tid));
    float u = fmaxf(TINYF, u01f(b) + TINYF);
    float g = -logf(-logf(u));            // precise: discrete decision
    sval[tid] = g + logw[tid];
    sidx[tid] = tid;
  }
  __syncthreads();
  for (int st = 128; st > 0; st >>= 1) {
    if (tid < st) {
      float va = sval[tid], vb = sval[tid + st];
      int ia = sidx[tid], ib = sidx[tid + st];
      if (vb > va || (vb == va && ib < ia)) { sval[tid] = vb; sidx[tid] = ib; }
    }
    __syncthreads();
  }
  int p = sidx[0];

  if (tid == 0) {
    used[p] = 1;                           // benign same-value race
    uint32_t i = rb_fold(kk.k2i0, kk.k2i1, (uint32_t)k) & 15u;
    uint32_t h = rb_fold(kk.k1o0, kk.k1o1, (uint32_t)k) % 15u;
    uint32_t l = rb_fold(kk.k2o0, kk.k2o1, (uint32_t)k) % 15u;
    uint32_t off = 1u + (h + l) % 15u;
    uint32_t j = (i + off) & 15u;
    int i1 = (int)(i < j ? i : j);
    int i2 = (int)(i < j ? j : i);
    sh_i1 = i1; sh_i2 = i2;

    const float SUBR = 1.0f - 1e-6f;
    float u1 = fmaxf(1e-6f, u01f(rb_fold(kk.ku10, kk.ku11, (uint32_t)k)) * SUBR + 1e-6f);
    float u2 = fmaxf(1e-6f, u01f(rb_fold(kk.ku20, kk.ku21, (uint32_t)k)) * SUBR + 1e-6f);
    float b1 = -0.1f * logf(u1);
    float b2 = -0.1f * logf(u2);
    w1w[k] = 1.0f - expf(-b1);
    w2w[k] = 1.0f - expf(-b2);
    i1w[k] = i1; i2w[k] = i2; pw[k] = p;

    float sb = b1 + b2;
    for (int r = 0; r < 16; r++) sb += b1r[p * 16 + r] + b2r[p * 16 + r];
    float prior = -sb / 0.1f - 34.0f * logf(0.1f);

    float topo_sum = 0.0f; int cnt = 0;
    for (int t = 0; t < 15; t++) {
      int lct;
      if (t == i1)      lct = lc[p * 16 + i1] + lc[p * 16 + i2];
      else if (t == i2) lct = lc[p * 16 + 15];
      else              lct = lc[p * 16 + t];
      int ti = 2 * lct - 3; ti = ti < 0 ? 0 : (ti > 63 ? 63 : ti);
      if (lct >= 2) topo_sum -= ldf[ti];
      if (lct > 1) cnt++;
    }
    float log_v_minus = logf(fmaxf((float)cnt, 1.0f));
    float log_v_plus = logf(120.0f);
    cw[k] = prior + topo_sum - logpi[p] + log_v_minus - log_v_plus;
  }
  __syncthreads();

  if (tid < 4) {
    int a = tid, i1 = sh_i1, i2 = sh_i2, p2 = sidx[0];
    const float* e1 = emb + ((size_t)p2 * 16 + i1) * 64;
    const float* e2 = emb + ((size_t)p2 * 16 + i2) * 64;
    float acc = 0.0f;
    for (int d = 0; d < 64; d++) acc += 0.5f * (e1[d] + e2[d]) * Wstat[d * 4 + a];
    enlm[k * 4 + a] = __expf(acc);
  }
}

// ---------------------------------------------------------------------------
// Kernel C: Lorig partials, only for used particles. Grid (4 sblk, 256 p).
// Accumulates in log2 domain; scales by ln2 once at the end.
// ---------------------------------------------------------------------------
__global__ __launch_bounds__(256) void k_lorig(
    const float* __restrict__ lfg, const float* __restrict__ eslw,
    const float* __restrict__ emb, const float* __restrict__ Wstat,
    const int* __restrict__ used, float* __restrict__ Lpart) {
  int p = blockIdx.y, sblk = blockIdx.x, tid = threadIdx.x;
  if (used[p] == 0) return;
  __shared__ float enl[64];
  __shared__ float sred[16 * 4];
  if (tid < 64) {
    int t = tid >> 2, a = tid & 3;
    const float4* e4 = (const float4*)(emb + ((size_t)p * 16 + t) * 64);
    float acc = 0.0f;
#pragma unroll
    for (int d4 = 0; d4 < 16; d4++) {
      float4 e = e4[d4];
      acc += e.x * Wstat[(d4 * 4 + 0) * 4 + a] + e.y * Wstat[(d4 * 4 + 1) * 4 + a] +
             e.z * Wstat[(d4 * 4 + 2) * 4 + a] + e.w * Wstat[(d4 * 4 + 3) * 4 + a];
    }
    enl[tid] = __expf(acc);
  }
  __syncthreads();
  int s = sblk * 256 + tid;
  const float4 esl = ((const float4*)eslw)[s];
  const float* base = lfg + (size_t)p * 65536;

  float acc[16];
#pragma unroll
  for (int t = 0; t < 16; t++) {
    float4 lf = *(const float4*)(base + t * 4096 + s * 4);
    float w0 = enl[t * 4 + 0] * esl.x, w1 = enl[t * 4 + 1] * esl.y;
    float w2 = enl[t * 4 + 2] * esl.z, w3 = enl[t * 4 + 3] * esl.w;
    float S1 = w0 + w1 + w2 + w3;
    float S2 = __expf(lf.x) * w0 + __expf(lf.y) * w1 +
               __expf(lf.z) * w2 + __expf(lf.w) * w3;
    acc[t] = __log2f(S2) - __log2f(S1);
  }
#pragma unroll
  for (int t = 0; t < 16; t++) {
    float v = acc[t];
    for (int o = 32; o > 0; o >>= 1) v += __shfl_down(v, o, 64);
    if ((tid & 63) == 0) sred[t * 4 + (tid >> 6)] = v;
  }
  __syncthreads();
  if (tid < 16) {
    float s4 = sred[tid * 4 + 0] + sred[tid * 4 + 1] + sred[tid * 4 + 2] + sred[tid * 4 + 3];
    Lpart[((size_t)p * 4 + sblk) * 16 + tid] = s4 * 0.69314718056f;  // ln2
  }
}

// ---------------------------------------------------------------------------
// Kernel D: merged-node term over sites + final combine. 256 blocks (k) x 1024.
// ---------------------------------------------------------------------------
__global__ __launch_bounds__(1024) void k_fin(
    const float* __restrict__ lfg, const float* __restrict__ eslw,
    const float* __restrict__ enlm, const float* __restrict__ w1w,
    const float* __restrict__ w2w, const int* __restrict__ pw,
    const int* __restrict__ i1w, const int* __restrict__ i2w,
    const float* __restrict__ cw, const float* __restrict__ Lpart,
    float* __restrict__ out) {
  int k = blockIdx.x, tid = threadIdx.x;
  __shared__ float sred[16];
  int p = pw[k], i1 = i1w[k], i2 = i2w[k];
  float w1 = w1w[k], w2 = w2w[k];
  float om1 = 1.0f - w1, om2 = 1.0f - w2;
  float m0 = enlm[k * 4 + 0], m1 = enlm[k * 4 + 1];
  float m2 = enlm[k * 4 + 2], m3 = enlm[k * 4 + 3];
  const float* base = lfg + (size_t)p * 65536;

  int s = tid;
  const float4 esl = ((const float4*)eslw)[s];
  float t0 = m0 * esl.x, t1 = m1 * esl.y, t2 = m2 * esl.z, t3 = m3 * esl.w;
  float T = t0 + t1 + t2 + t3;
  float invT = 1.0f / T;
  float4 lf1 = *(const float4*)(base + i1 * 4096 + s * 4);
  float4 lf2 = *(const float4*)(base + i2 * 4096 + s * 4);
  float f10 = __expf(lf1.x), f11 = __expf(lf1.y), f12 = __expf(lf1.z), f13 = __expf(lf1.w);
  float f20 = __expf(lf2.x), f21 = __expf(lf2.y), f22 = __expf(lf2.z), f23 = __expf(lf2.w);
  float dot1 = (t0 * f10 + t1 * f11 + t2 * f12 + t3 * f13) * invT;
  float dot2 = (t0 * f20 + t1 * f21 + t2 * f22 + t3 * f23) * invT;
  float n0 = __logf(om1 * f10 + w1 * dot1 + 1e-30f) + __logf(om2 * f20 + w2 * dot2 + 1e-30f);
  float n1 = __logf(om1 * f11 + w1 * dot1 + 1e-30f) + __logf(om2 * f21 + w2 * dot2 + 1e-30f);
  float n2 = __logf(om1 * f12 + w1 * dot1 + 1e-30f) + __logf(om2 * f22 + w2 * dot2 + 1e-30f);
  float n3 = __logf(om1 * f13 + w1 * dot1 + 1e-30f) + __logf(om2 * f23 + w2 * dot2 + 1e-30f);
  float S2 = __expf(n0) * t0 + __expf(n1) * t1 + __expf(n2) * t2 + __expf(n3) * t3;
  float tot = __logf(S2) - __logf(T);

  for (int o = 32; o > 0; o >>= 1) tot += __shfl_down(tot, o, 64);
  if ((tid & 63) == 0) sred[tid >> 6] = tot;
  __syncthreads();
  if (tid < 64) {
    // Lpart layout [p][sblk(4)][t(16)]: slot t = tid & 15.
    int t = tid & 15;
    float coef = (t == i1 || t == i2) ? 0.0f : 1.0f;
    float v = coef * Lpart[(size_t)p * 64 + tid];
    if (tid < 16) v += sred[tid];
    for (int o = 32; o > 0; o >>= 1) v += __shfl_down(v, o, 64);
    if (tid == 0) out[k] = cw[k] + v;
  }
}

// ---------------------------------------------------------------------------
extern "C" void kernel_launch(void* const* d_in, const int* in_sizes, int n_in,
                              void* d_out, int out_size, void* d_ws, size_t ws_size,
                              hipStream_t stream) {
  const float* logw  = (const float*)d_in[0];
  const float* b1r   = (const float*)d_in[1];
  const float* b2r   = (const float*)d_in[2];
  const int*   lc    = (const int*)d_in[3];
  const float* emb   = (const float*)d_in[4];
  const float* lfg   = (const float*)d_in[5];
  const float* logpi = (const float*)d_in[6];
  const float* site  = (const float*)d_in[7];
  const float* Wstat = (const float*)d_in[8];
  const float* Wsite = (const float*)d_in[9];
  const float* ldf   = (const float*)d_in[10];

  char* w = (char*)d_ws;
  float* eslw  = (float*)w; w += 1024 * 4 * 4;
  float* enlm  = (float*)w; w += 256 * 4 * 4;
  float* w1w   = (float*)w; w += 256 * 4;
  float* w2w   = (float*)w; w += 256 * 4;
  float* cw    = (float*)w; w += 256 * 4;
  int*   pw    = (int*)w;   w += 256 * 4;
  int*   i1w   = (int*)w;   w += 256 * 4;
  int*   i2w   = (int*)w;   w += 256 * 4;
  int*   used  = (int*)w;   w += 256 * 4;
  float* Lpart = (float*)w; w += 256 * 64 * 4;

  uint32_t S0[5], S1[5];
  for (uint32_t i = 0; i < 5; i++) tf2x32(0u, 42u, 0u, i, S0[i], S1[i]);
  Keys kk;
  kk.kres0 = S0[0]; kk.kres1 = S1[0];
  kk.ku10  = S0[3]; kk.ku11  = S1[3];
  kk.ku20  = S0[4]; kk.ku21  = S1[4];
  {
    uint32_t a0, a1, b0, b1;
    tf2x32(S0[1], S1[1], 0u, 0u, a0, a1);
    tf2x32(S0[1], S1[1], 0u, 1u, b0, b1);
    (void)a0; (void)a1;
    kk.k2i0 = b0; kk.k2i1 = b1;
  }
  {
    uint32_t a0, a1, b0, b1;
    tf2x32(S0[2], S1[2], 0u, 0u, a0, a1);
    tf2x32(S0[2], S1[2], 0u, 1u, b0, b1);
    kk.k1o0 = a0; kk.k1o1 = a1;
    kk.k2o0 = b0; kk.k2o1 = b1;
  }

  k_pre<<<4, 256, 0, stream>>>(site, Wsite, eslw, used);
  k_setup<<<256, 256, 0, stream>>>(logw, b1r, b2r, lc, emb, logpi, Wstat, ldf,
                                   enlm, w1w, w2w, cw, pw, i1w, i2w, used, kk);
  dim3 gC(4, 256);
  k_lorig<<<gC, 256, 0, stream>>>(lfg, eslw, emb, Wstat, used, Lpart);
  k_fin<<<256, 1024, 0, stream>>>(lfg, eslw, enlm, w1w, w2w, pw, i1w, i2w,
                                  cw, Lpart, (float*)d_out);
}